// Round 2
// baseline (674.764 us; speedup 1.0000x reference)
//
#include <hip/hip_runtime.h>

#define DH 64

__device__ __forceinline__ float lane_bcast(float v, int k) {
  return __int_as_float(__builtin_amdgcn_readlane(__float_as_int(v), k));
}

__global__ __launch_bounds__(256) void k_count(const int* __restrict__ dst,
                                               int* __restrict__ degi, int e) {
  int i = blockIdx.x * 256 + threadIdx.x;
  if (i < e) atomicAdd(&degi[dst[i]], 1);
}

__global__ __launch_bounds__(256) void k_dinv(const int* __restrict__ degi,
                                              float* __restrict__ dinv, int n) {
  int i = blockIdx.x * 256 + threadIdx.x;
  if (i < n) dinv[i] = 1.0f / sqrtf((float)degi[i] + 1.0f);
}

// Single-block exclusive scan of degi[0..n) -> off[0..n], plus cursor copy.
__global__ __launch_bounds__(1024) void k_scan(const int* __restrict__ degi,
    int* __restrict__ off, int* __restrict__ cursor, int n, int e)
{
  __shared__ int sc[1024];
  const int t = threadIdx.x;
  const int chunk = (n + 1023) >> 10;
  const int lo = t * chunk;
  const int hi = min(n, lo + chunk);
  int s = 0;
  for (int i = lo; i < hi; i++) s += degi[i];
  sc[t] = s;
  __syncthreads();
  for (int d = 1; d < 1024; d <<= 1) {
    int v = (t >= d) ? sc[t - d] : 0;
    __syncthreads();
    sc[t] += v;
    __syncthreads();
  }
  int run = sc[t] - s;  // exclusive base for this chunk
  for (int i = lo; i < hi; i++) {
    off[i] = run; cursor[i] = run; run += degi[i];
  }
  if (t == 0) off[n] = e;
}

__global__ __launch_bounds__(256) void k_fill(const int* __restrict__ src,
    const int* __restrict__ dst, int* __restrict__ cursor,
    int* __restrict__ csr, int e)
{
  int i = blockIdx.x * 256 + threadIdx.x;
  if (i < e) {
    int p = atomicAdd(&cursor[dst[i]], 1);
    csr[p] = src[i];
  }
}

// hn[r][c] = (X@W)[r][c] * dinv[r].
// APPLY: input X is previous layer's pre-BN y; apply relu(y*scale+shift) on load.
template<int K, bool APPLY>
__global__ __launch_bounds__(256) void k_gemm(const float* __restrict__ X,
    const float* __restrict__ W, const float* __restrict__ dinv,
    const float* __restrict__ ss, float* __restrict__ hn, int n)
{
  __shared__ float Wl[K * DH];
  for (int i = threadIdx.x; i < K * DH; i += 256) Wl[i] = W[i];
  __syncthreads();
  const int lane = threadIdx.x & 63;
  const int wid = blockIdx.x * 4 + (threadIdx.x >> 6);
  const int r0 = wid * 4;
  if (r0 >= n) return;
  float sc = 0.f, sh = 0.f;
  if (APPLY) { sc = ss[lane]; sh = ss[DH + lane]; }
  float xa[4], xb[4], acc[4];
  #pragma unroll
  for (int i = 0; i < 4; i++) {
    int r = r0 + i; if (r > n - 1) r = n - 1;
    const float* xr = X + (size_t)r * K;
    float v = xr[lane];
    if (APPLY) v = fmaxf(0.f, fmaf(v, sc, sh));
    xa[i] = v;
    if (K == 128) {
      float v2 = xr[DH + lane];
      if (APPLY) v2 = fmaxf(0.f, fmaf(v2, sc, sh));  // unreachable (K=128 only layer 0) but harmless
      xb[i] = v2;
    }
    acc[i] = 0.f;
  }
  #pragma unroll
  for (int k = 0; k < DH; k++) {
    float w = Wl[k * DH + lane];
    #pragma unroll
    for (int i = 0; i < 4; i++) acc[i] = fmaf(lane_bcast(xa[i], k), w, acc[i]);
  }
  if (K == 128) {
    #pragma unroll
    for (int k = 0; k < DH; k++) {
      float w = Wl[(DH + k) * DH + lane];
      #pragma unroll
      for (int i = 0; i < 4; i++) acc[i] = fmaf(lane_bcast(xb[i], k), w, acc[i]);
    }
  }
  #pragma unroll
  for (int i = 0; i < 4; i++) {
    if (r0 + i < n) hn[(size_t)(r0 + i) * DH + lane] = acc[i] * dinv[r0 + i];
  }
}

// Fused: agg = hn[d] + sum_{j in bucket(d)} hn[csr[j]];
// y = agg*dinv[d] + b; accumulate per-column BN stats into S.
__global__ __launch_bounds__(256) void k_aggbn(const float* __restrict__ hn,
    const int* __restrict__ off, const int* __restrict__ csr,
    const float* __restrict__ dinv, const float* __restrict__ b,
    float* __restrict__ y, float* __restrict__ S, int n)
{
  const int lane = threadIdx.x & 63;
  const int w = threadIdx.x >> 6;
  const int wid = blockIdx.x * 4 + w;
  const int nw = gridDim.x * 4;
  float bias = b[lane];
  float s1 = 0.f, s2 = 0.f;
  for (int d = wid; d < n; d += nw) {
    float acc = hn[(size_t)d * DH + lane];  // self-loop term
    float acc2 = 0.f;
    int j = off[d];
    const int end = off[d + 1];
    for (; j + 1 < end; j += 2) {
      int sA = csr[j], sB = csr[j + 1];
      acc  += hn[(size_t)sA * DH + lane];
      acc2 += hn[(size_t)sB * DH + lane];
    }
    if (j < end) acc += hn[(size_t)csr[j] * DH + lane];
    float v = fmaf(acc + acc2, dinv[d], bias);
    y[(size_t)d * DH + lane] = v;
    s1 += v;
    s2 = fmaf(v, v, s2);
  }
  __shared__ float L[8][DH];
  L[w][lane] = s1; L[4 + w][lane] = s2;
  __syncthreads();
  if (threadIdx.x < DH) {
    float t1 = L[0][lane] + L[1][lane] + L[2][lane] + L[3][lane];
    float t2 = L[4][lane] + L[5][lane] + L[6][lane] + L[7][lane];
    atomicAdd(&S[lane], t1);
    atomicAdd(&S[DH + lane], t2);
  }
}

__global__ __launch_bounds__(64) void k_scaleshift(const float* __restrict__ S,
    const float* __restrict__ gamma, const float* __restrict__ beta,
    float* __restrict__ ss, float inv_n)
{
  int c = threadIdx.x;
  float mu = S[c] * inv_n;
  float var = S[DH + c] * inv_n - mu * mu;
  float scv = gamma[c] / sqrtf(var + 1e-5f);
  ss[c] = scv;
  ss[DH + c] = fmaf(-mu, scv, beta[c]);
}

// out[r] = sum_c relu(y[r][c]*scale+shift) * Wout[c] + bout
__global__ __launch_bounds__(256) void k_out(const float* __restrict__ y,
    const float* __restrict__ ss, const float* __restrict__ Wout,
    const float* __restrict__ bout, float* __restrict__ out, int n)
{
  const int lane = threadIdx.x & 63;
  const int wid = blockIdx.x * 4 + (threadIdx.x >> 6);
  const int nw = gridDim.x * 4;
  float wv = Wout[lane];
  float sc = ss[lane], sh = ss[DH + lane];
  float bo = bout[0];
  for (int r = wid; r < n; r += nw) {
    float v = fmaxf(0.f, fmaf(y[(size_t)r * DH + lane], sc, sh)) * wv;
    #pragma unroll
    for (int off = 32; off; off >>= 1) v += __shfl_xor(v, off);
    if (lane == 0) out[r] = v + bo;
  }
}

extern "C" void kernel_launch(void* const* d_in, const int* in_sizes, int n_in,
                              void* d_out, int out_size, void* d_ws, size_t ws_size,
                              hipStream_t stream) {
  const float* x     = (const float*)d_in[0];
  const int*   ei    = (const int*)  d_in[1];
  const float* W0    = (const float*)d_in[2];
  const float* b0    = (const float*)d_in[3];
  const float* W1    = (const float*)d_in[4];
  const float* b1    = (const float*)d_in[5];
  const float* W2    = (const float*)d_in[6];
  const float* b2    = (const float*)d_in[7];
  const float* gamma = (const float*)d_in[8];
  const float* beta  = (const float*)d_in[9];
  const float* Wout  = (const float*)d_in[10];
  const float* bout  = (const float*)d_in[11];
  float* out = (float*)d_out;

  const int n = in_sizes[0] / 128;  // d_in = 128
  const int e = in_sizes[1] / 2;
  const int* src = ei;
  const int* dst = ei + e;

  // Workspace layout (4-byte elements), 64-elem aligned blocks.
  auto a64 = [](size_t v) { return (v + 63) & ~(size_t)63; };
  char* ws = (char*)d_ws;
  size_t o_degi = 0;                         // int[n]    (zeroed)
  size_t o_S    = a64(o_degi + n);           // f32[3*128] (zeroed)
  size_t o_off  = a64(o_S + 3 * 2 * DH);     // int[n+1]
  size_t o_cur  = a64(o_off + n + 1);        // int[n]
  size_t o_csr  = a64(o_cur + n);            // int[e]
  size_t o_dinv = a64(o_csr + e);            // f32[n]
  size_t o_hn   = a64(o_dinv + n);           // f32[n*64]
  size_t o_y    = o_hn + (size_t)n * DH;     // f32[n*64]
  size_t o_ss   = o_y + (size_t)n * DH;      // f32[3*128]
  int*   degi  = (int*)  (ws + o_degi * 4);
  float* S     = (float*)(ws + o_S * 4);
  int*   off   = (int*)  (ws + o_off * 4);
  int*   cur   = (int*)  (ws + o_cur * 4);
  int*   csr   = (int*)  (ws + o_csr * 4);
  float* dinv  = (float*)(ws + o_dinv * 4);
  float* hn    = (float*)(ws + o_hn * 4);
  float* y     = (float*)(ws + o_y * 4);
  float* ss    = (float*)(ws + o_ss * 4);

  // Zero degi + BN-stat accumulators in one memset (they are adjacent).
  hipMemsetAsync(ws, 0, o_off * 4, stream);

  // CSR build (once; reused by all 3 layers).
  k_count<<<(e + 255) / 256, 256, 0, stream>>>(dst, degi, e);
  k_dinv<<<(n + 255) / 256, 256, 0, stream>>>(degi, dinv, n);
  k_scan<<<1, 1024, 0, stream>>>(degi, off, cur, n, e);
  k_fill<<<(e + 255) / 256, 256, 0, stream>>>(src, dst, cur, csr, e);

  const int gemm_blocks = (n + 15) / 16;  // 4 waves/block * 4 rows/wave

  // Layer 0
  k_gemm<128, false><<<gemm_blocks, 256, 0, stream>>>(x, W0, dinv, nullptr, hn, n);
  k_aggbn<<<1024, 256, 0, stream>>>(hn, off, csr, dinv, b0, y, S + 0 * 128, n);
  k_scaleshift<<<1, 64, 0, stream>>>(S + 0 * 128, gamma + 0 * DH, beta + 0 * DH,
                                     ss + 0 * 128, 1.0f / (float)n);
  // Layer 1 (BN+ReLU of layer 0 fused into GEMM load)
  k_gemm<64, true><<<gemm_blocks, 256, 0, stream>>>(y, W1, dinv, ss + 0 * 128, hn, n);
  k_aggbn<<<1024, 256, 0, stream>>>(hn, off, csr, dinv, b1, y, S + 1 * 128, n);
  k_scaleshift<<<1, 64, 0, stream>>>(S + 1 * 128, gamma + 1 * DH, beta + 1 * DH,
                                     ss + 1 * 128, 1.0f / (float)n);
  // Layer 2
  k_gemm<64, true><<<gemm_blocks, 256, 0, stream>>>(y, W2, dinv, ss + 1 * 128, hn, n);
  k_aggbn<<<1024, 256, 0, stream>>>(hn, off, csr, dinv, b2, y, S + 2 * 128, n);
  k_scaleshift<<<1, 64, 0, stream>>>(S + 2 * 128, gamma + 2 * DH, beta + 2 * DH,
                                     ss + 2 * 128, 1.0f / (float)n);
  // Output projection (BN+ReLU of layer 2 fused)
  k_out<<<512, 256, 0, stream>>>(y, ss + 2 * 128, Wout, bout, out, n);
}

// Round 4
// 513.190 us; speedup vs baseline: 1.3148x; 1.3148x over previous
//
#include <hip/hip_runtime.h>

#define DH 64

__device__ __forceinline__ float lane_bcast(float v, int k) {
  return __int_as_float(__builtin_amdgcn_readlane(__float_as_int(v), k));
}

__global__ __launch_bounds__(256) void k_count(const int* __restrict__ dst,
                                               int* __restrict__ degi, int e) {
  int i = blockIdx.x * 256 + threadIdx.x;
  if (i < e) atomicAdd(&degi[dst[i]], 1);
}

// Per-block scan: local exclusive prefix -> loc (=cursor buf), block total -> partial.
// dinv computation fused (reads degi anyway).
__global__ __launch_bounds__(256) void k_scan1(const int* __restrict__ degi,
    float* __restrict__ dinv, int* __restrict__ loc, int* __restrict__ partial, int n)
{
  const int t = threadIdx.x;
  const int i = blockIdx.x * 256 + t;
  int v = (i < n) ? degi[i] : 0;
  if (i < n) dinv[i] = 1.0f / sqrtf((float)v + 1.0f);
  __shared__ int sc[256];
  sc[t] = v;
  __syncthreads();
  #pragma unroll
  for (int d = 1; d < 256; d <<= 1) {
    int u = (t >= d) ? sc[t - d] : 0;
    __syncthreads();
    sc[t] += u;
    __syncthreads();
  }
  if (i < n) loc[i] = sc[t] - v;              // local exclusive
  if (t == 255) partial[blockIdx.x] = sc[t];  // block total
}

// base = sum(partial[0..blockIdx)); off = loc + base; cursor = off; off[n] = e.
__global__ __launch_bounds__(256) void k_scan2(const int* __restrict__ partial,
    int* __restrict__ loc_cursor, int* __restrict__ off, int n, int e)
{
  const int t = threadIdx.x;
  __shared__ int red[256];
  int s = 0;
  for (int i = t; i < (int)blockIdx.x; i += 256) s += partial[i];
  red[t] = s;
  __syncthreads();
  #pragma unroll
  for (int d = 128; d; d >>= 1) {
    if (t < d) red[t] += red[t + d];
    __syncthreads();
  }
  const int base = red[0];
  const int i = blockIdx.x * 256 + t;
  if (i < n) {
    int o = loc_cursor[i] + base;
    off[i] = o;
    loc_cursor[i] = o;  // becomes the fill cursor
  }
  if (i == n) off[n] = e;
}

__global__ __launch_bounds__(256) void k_fill(const int* __restrict__ src,
    const int* __restrict__ dst, int* __restrict__ cursor,
    int* __restrict__ csr, int e)
{
  int i = blockIdx.x * 256 + threadIdx.x;
  if (i < e) {
    int p = atomicAdd(&cursor[dst[i]], 1);
    csr[p] = src[i];
  }
}

// hn[r][c] = (X@W)[r][c] * dinv[r].
// APPLY: input X is previous layer's pre-BN y; apply relu(y*scale+shift) on load.
template<int K, bool APPLY>
__global__ __launch_bounds__(256) void k_gemm(const float* __restrict__ X,
    const float* __restrict__ W, const float* __restrict__ dinv,
    const float* __restrict__ ss, float* __restrict__ hn, int n)
{
  __shared__ float Wl[K * DH];
  for (int i = threadIdx.x; i < K * DH; i += 256) Wl[i] = W[i];
  __syncthreads();
  const int lane = threadIdx.x & 63;
  const int wid = blockIdx.x * 4 + (threadIdx.x >> 6);
  const int r0 = wid * 4;
  if (r0 >= n) return;
  float sc = 0.f, sh = 0.f;
  if (APPLY) { sc = ss[lane]; sh = ss[DH + lane]; }
  float xa[4], xb[4], acc[4];
  #pragma unroll
  for (int i = 0; i < 4; i++) {
    int r = r0 + i; if (r > n - 1) r = n - 1;
    const float* xr = X + (size_t)r * K;
    float v = xr[lane];
    if (APPLY) v = fmaxf(0.f, fmaf(v, sc, sh));
    xa[i] = v;
    if (K == 128) xb[i] = xr[DH + lane];
    acc[i] = 0.f;
  }
  #pragma unroll
  for (int k = 0; k < DH; k++) {
    float w = Wl[k * DH + lane];
    #pragma unroll
    for (int i = 0; i < 4; i++) acc[i] = fmaf(lane_bcast(xa[i], k), w, acc[i]);
  }
  if (K == 128) {
    #pragma unroll
    for (int k = 0; k < DH; k++) {
      float w = Wl[(DH + k) * DH + lane];
      #pragma unroll
      for (int i = 0; i < 4; i++) acc[i] = fmaf(lane_bcast(xb[i], k), w, acc[i]);
    }
  }
  #pragma unroll
  for (int i = 0; i < 4; i++) {
    if (r0 + i < n) hn[(size_t)(r0 + i) * DH + lane] = acc[i] * dinv[r0 + i];
  }
}

// Fused: agg = hn[d] + sum_{j in bucket(d)} hn[csr[j]];
// y = agg*dinv[d] + b; accumulate per-column BN stats into S.
// wid made wave-uniform via readfirstlane so off/csr/dinv loads scalarize
// (s_load), keeping the vector-memory pipe free for the hn gathers.
__global__ __launch_bounds__(256) void k_aggbn(const float* __restrict__ hn,
    const int* __restrict__ off, const int* __restrict__ csr,
    const float* __restrict__ dinv, const float* __restrict__ b,
    float* __restrict__ y, float* __restrict__ S, int n)
{
  const int lane = threadIdx.x & 63;
  const int w = threadIdx.x >> 6;
  const int wid = __builtin_amdgcn_readfirstlane(blockIdx.x * 4 + w);
  const int nw = gridDim.x * 4;
  float bias = b[lane];
  float s1 = 0.f, s2 = 0.f;
  for (int d = wid; d < n; d += nw) {
    const size_t base = (size_t)d * DH + lane;
    float a0 = hn[base];  // self-loop term
    float a1 = 0.f, a2 = 0.f, a3 = 0.f;
    int j = off[d];
    const int end = off[d + 1];
    for (; j + 3 < end; j += 4) {
      int e0 = csr[j], e1 = csr[j + 1], e2 = csr[j + 2], e3 = csr[j + 3];
      a0 += hn[(size_t)e0 * DH + lane];
      a1 += hn[(size_t)e1 * DH + lane];
      a2 += hn[(size_t)e2 * DH + lane];
      a3 += hn[(size_t)e3 * DH + lane];
    }
    for (; j < end; j++) a0 += hn[(size_t)csr[j] * DH + lane];
    float v = fmaf((a0 + a1) + (a2 + a3), dinv[d], bias);
    y[base] = v;
    s1 += v;
    s2 = fmaf(v, v, s2);
  }
  __shared__ float L[8][DH];
  L[w][lane] = s1; L[4 + w][lane] = s2;
  __syncthreads();
  if (threadIdx.x < DH) {
    float t1 = L[0][lane] + L[1][lane] + L[2][lane] + L[3][lane];
    float t2 = L[4][lane] + L[5][lane] + L[6][lane] + L[7][lane];
    atomicAdd(&S[lane], t1);
    atomicAdd(&S[DH + lane], t2);
  }
}

__global__ __launch_bounds__(64) void k_scaleshift(const float* __restrict__ S,
    const float* __restrict__ gamma, const float* __restrict__ beta,
    float* __restrict__ ss, float inv_n)
{
  int c = threadIdx.x;
  float mu = S[c] * inv_n;
  float var = S[DH + c] * inv_n - mu * mu;
  float scv = gamma[c] / sqrtf(var + 1e-5f);
  ss[c] = scv;
  ss[DH + c] = fmaf(-mu, scv, beta[c]);
}

// out[r] = sum_c relu(y[r][c]*scale+shift) * Wout[c] + bout
__global__ __launch_bounds__(256) void k_out(const float* __restrict__ y,
    const float* __restrict__ ss, const float* __restrict__ Wout,
    const float* __restrict__ bout, float* __restrict__ out, int n)
{
  const int lane = threadIdx.x & 63;
  const int wid = blockIdx.x * 4 + (threadIdx.x >> 6);
  const int nw = gridDim.x * 4;
  float wv = Wout[lane];
  float sc = ss[lane], sh = ss[DH + lane];
  float bo = bout[0];
  for (int r = wid; r < n; r += nw) {
    float v = fmaxf(0.f, fmaf(y[(size_t)r * DH + lane], sc, sh)) * wv;
    #pragma unroll
    for (int off = 32; off; off >>= 1) v += __shfl_xor(v, off);
    if (lane == 0) out[r] = v + bo;
  }
}

extern "C" void kernel_launch(void* const* d_in, const int* in_sizes, int n_in,
                              void* d_out, int out_size, void* d_ws, size_t ws_size,
                              hipStream_t stream) {
  const float* x     = (const float*)d_in[0];
  const int*   ei    = (const int*)  d_in[1];
  const float* W0    = (const float*)d_in[2];
  const float* b0    = (const float*)d_in[3];
  const float* W1    = (const float*)d_in[4];
  const float* b1    = (const float*)d_in[5];
  const float* W2    = (const float*)d_in[6];
  const float* b2    = (const float*)d_in[7];
  const float* gamma = (const float*)d_in[8];
  const float* beta  = (const float*)d_in[9];
  const float* Wout  = (const float*)d_in[10];
  const float* bout  = (const float*)d_in[11];
  float* out = (float*)d_out;

  const int n = in_sizes[0] / 128;  // d_in = 128
  const int e = in_sizes[1] / 2;
  const int* src = ei;
  const int* dst = ei + e;

  const int nblk_scan = (n + 255) / 256;

  // Workspace layout (4-byte elements), 64-elem aligned blocks.
  auto a64 = [](size_t v) { return (v + 63) & ~(size_t)63; };
  char* ws = (char*)d_ws;
  size_t o_degi = 0;                          // int[n]    (zeroed)
  size_t o_S    = a64(o_degi + n);            // f32[3*128] (zeroed)
  size_t o_part = a64(o_S + 3 * 2 * DH);      // int[nblk_scan]
  size_t o_off  = a64(o_part + nblk_scan);    // int[n+1]
  size_t o_cur  = a64(o_off + n + 1);         // int[n]  (scan loc -> fill cursor)
  size_t o_csr  = a64(o_cur + n);             // int[e]
  size_t o_dinv = a64(o_csr + e);             // f32[n]
  size_t o_hn   = a64(o_dinv + n);            // f32[n*64]
  size_t o_y    = o_hn + (size_t)n * DH;      // f32[n*64]
  size_t o_ss   = o_y + (size_t)n * DH;       // f32[3*128]
  int*   degi  = (int*)  (ws + o_degi * 4);
  float* S     = (float*)(ws + o_S * 4);
  int*   part  = (int*)  (ws + o_part * 4);
  int*   off   = (int*)  (ws + o_off * 4);
  int*   cur   = (int*)  (ws + o_cur * 4);
  int*   csr   = (int*)  (ws + o_csr * 4);
  float* dinv  = (float*)(ws + o_dinv * 4);
  float* hn    = (float*)(ws + o_hn * 4);
  float* y     = (float*)(ws + o_y * 4);
  float* ss    = (float*)(ws + o_ss * 4);

  // Zero degi + BN-stat accumulators in one memset (they are adjacent).
  hipMemsetAsync(ws, 0, o_part * 4, stream);

  // CSR build (once; reused by all 3 layers).
  k_count<<<(e + 255) / 256, 256, 0, stream>>>(dst, degi, e);
  k_scan1<<<nblk_scan, 256, 0, stream>>>(degi, dinv, cur, part, n);
  k_scan2<<<nblk_scan, 256, 0, stream>>>(part, cur, off, n, e);
  k_fill<<<(e + 255) / 256, 256, 0, stream>>>(src, dst, cur, csr, e);

  const int gemm_blocks = (n + 15) / 16;  // 4 waves/block * 4 rows/wave

  // Layer 0
  k_gemm<128, false><<<gemm_blocks, 256, 0, stream>>>(x, W0, dinv, nullptr, hn, n);
  k_aggbn<<<2048, 256, 0, stream>>>(hn, off, csr, dinv, b0, y, S + 0 * 128, n);
  k_scaleshift<<<1, 64, 0, stream>>>(S + 0 * 128, gamma + 0 * DH, beta + 0 * DH,
                                     ss + 0 * 128, 1.0f / (float)n);
  // Layer 1 (BN+ReLU of layer 0 fused into GEMM load)
  k_gemm<64, true><<<gemm_blocks, 256, 0, stream>>>(y, W1, dinv, ss + 0 * 128, hn, n);
  k_aggbn<<<2048, 256, 0, stream>>>(hn, off, csr, dinv, b1, y, S + 1 * 128, n);
  k_scaleshift<<<1, 64, 0, stream>>>(S + 1 * 128, gamma + 1 * DH, beta + 1 * DH,
                                     ss + 1 * 128, 1.0f / (float)n);
  // Layer 2
  k_gemm<64, true><<<gemm_blocks, 256, 0, stream>>>(y, W2, dinv, ss + 1 * 128, hn, n);
  k_aggbn<<<2048, 256, 0, stream>>>(hn, off, csr, dinv, b2, y, S + 2 * 128, n);
  k_scaleshift<<<1, 64, 0, stream>>>(S + 2 * 128, gamma + 2 * DH, beta + 2 * DH,
                                     ss + 2 * 128, 1.0f / (float)n);
  // Output projection (BN+ReLU of layer 2 fused)
  k_out<<<512, 256, 0, stream>>>(y, ss + 2 * 128, Wout, bout, out, n);
}